// Round 18
// baseline (219.252 us; speedup 1.0000x reference)
//
#include <hip/hip_runtime.h>
#include <math.h>

#define SEQ    2048
#define DIMM   512
#define SH     128
#define EXP    1024
#define PROJ_  2176
#define NBATCH 8
#define ROWS   16384  // NBATCH*SEQ

#define KER_SCALE     16384.0f
#define KER_SCALE_INV (1.0f / 16384.0f)
#define QK_INV        (1.0f / (4096.0f * 2048.0f))   // q,k scaled x64 each; /MAX_LEN
#define W8            64.0f                          // generic fp8 pre-scale
#define INV4096       (1.0f / 4096.0f)               // undo x64 * x64

typedef __attribute__((ext_vector_type(4))) float floatx4;
typedef __attribute__((ext_vector_type(8))) int   int8v;

__device__ __forceinline__ unsigned short f2bf(float f) {
  union { float f; unsigned int u; } v; v.f = f;
  unsigned int r = (v.u + 0x7fffu + ((v.u >> 16) & 1u)) >> 16;
  return (unsigned short)r;
}
__device__ __forceinline__ float bf2f(unsigned short h) {
  union { unsigned int u; float f; } v; v.u = ((unsigned int)h) << 16;
  return v.f;
}
__device__ __forceinline__ unsigned char f2fp8(float f) {
  return (unsigned char)(__builtin_amdgcn_cvt_pk_fp8_f32(f, 0.0f, 0, false) & 0xffu);
}
__device__ __forceinline__ unsigned int pk4fp8(float a, float b, float c, float d) {
  unsigned int w = __builtin_amdgcn_cvt_pk_fp8_f32(a, b, 0, false);
  return __builtin_amdgcn_cvt_pk_fp8_f32(c, d, w, true);
}
__device__ __forceinline__ float fp82f(unsigned char b) {
  int e = (b >> 3) & 15, m = b & 7;
  float v = ldexpf((float)(e ? (8 + m) : m), (e ? e : 1) - 10);
  return (b & 0x80) ? -v : v;
}

// hardware fp8(e4m3, OCP)->f32 decode; sel MUST be a literal constant 0..3
#if defined(__has_builtin)
#if __has_builtin(__builtin_amdgcn_cvt_f32_fp8)
#define HAVE_HW_FP8DEC 1
#endif
#endif
#ifdef HAVE_HW_FP8DEC
#define FP8DEC0(w) __builtin_amdgcn_cvt_f32_fp8((w), 0)
#define FP8DEC1(w) __builtin_amdgcn_cvt_f32_fp8((w), 1)
#define FP8DEC2(w) __builtin_amdgcn_cvt_f32_fp8((w), 2)
#define FP8DEC3(w) __builtin_amdgcn_cvt_f32_fp8((w), 3)
#else
#define FP8DEC0(w) fp82f((unsigned char)((w)))
#define FP8DEC1(w) fp82f((unsigned char)((w) >> 8))
#define FP8DEC2(w) fp82f((unsigned char)((w) >> 16))
#define FP8DEC3(w) fp82f((unsigned char)((w) >> 24))
#endif

__device__ __forceinline__ void async16(const void* g, void* l) {
  __builtin_amdgcn_global_load_lds(
      (const __attribute__((address_space(1))) void*)g,
      (__attribute__((address_space(3))) void*)l, 16, 0, 0);
}

// =================== fused prep (256 threads) ===================
__device__ __forceinline__ void transpose_tile_fp8(const float* __restrict__ in,
                                                   unsigned char* __restrict__ out,
                                                   int R, int C, int bx, int by, float* tile) {
  int tx = threadIdx.x & 31, ty = threadIdx.x >> 5;
  int c0 = bx * 32, r0 = by * 32;
  #pragma unroll
  for (int j = 0; j < 32; j += 8)
    tile[(ty + j) * 33 + tx] = in[(long)(r0 + ty + j) * C + c0 + tx];
  __syncthreads();
  #pragma unroll
  for (int j = 0; j < 32; j += 8)
    out[(long)(c0 + ty + j) * R + r0 + tx] = f2fp8(tile[tx * 33 + ty + j] * W8);
}

__global__ void prep_kernel(const float* __restrict__ x, const float* __restrict__ ns,
                            unsigned char* __restrict__ xq,
                            const float* __restrict__ W1, unsigned char* __restrict__ w1q,
                            const float* __restrict__ W2, unsigned char* __restrict__ w2q,
                            const float* __restrict__ ra, const float* __restrict__ rb,
                            float* __restrict__ tpl) {
  __shared__ float sh[33 * 32];
  const int b = blockIdx.x, tid = threadIdx.x;
  if (b < 4096) {
    // ---- RMSNorm -> fp8 x64: 4 rows per block ----
    int wave = tid >> 6, lane = tid & 63;
    long row = (long)b * 4 + wave;
    const float4* xr = (const float4*)(x + row * DIMM);
    float4 v0 = xr[lane], v1 = xr[lane + 64];
    float ss = v0.x*v0.x + v0.y*v0.y + v0.z*v0.z + v0.w*v0.w
             + v1.x*v1.x + v1.y*v1.y + v1.z*v1.z + v1.w*v1.w;
    #pragma unroll
    for (int o = 32; o > 0; o >>= 1) ss += __shfl_xor(ss, o);
    float sc = rsqrtf(ss * (1.0f / DIMM) + 1e-6f) * ns[0] * W8;
    uint2 pk;
    pk.x = pk4fp8(v0.x*sc, v0.y*sc, v0.z*sc, v0.w*sc);
    pk.y = pk4fp8(v1.x*sc, v1.y*sc, v1.z*sc, v1.w*sc);
    ((uint2*)(xq + row * DIMM))[lane] = pk;
  } else if (b < 6144) {
    // ---- toeplitz diagonals, paired: tpl(d)=Sc+Ss, tpl(-d)=Sc-Ss ----
    const int d = b - 4096;          // 0..2047
    float sc_ = 0.0f, ss_ = 0.0f;
    for (int k = tid; k < 1024; k += 256) {
      float a1 = ra[k], a2 = ra[k + 1024];
      float b1v = rb[k], b2v = rb[k + 1024];
      float p = a1 * b1v + a2 * b2v;
      float q = a1 * b2v - a2 * b1v;
      float th = exp2f((float)k * (-13.287712379549449f / 1024.0f));
      float ang = (float)d * th;
      sc_ += p * cosf(ang);
      ss_ += q * sinf(ang);
    }
    #pragma unroll
    for (int o = 32; o > 0; o >>= 1) {
      sc_ += __shfl_xor(sc_, o);
      ss_ += __shfl_xor(ss_, o);
    }
    int wave = tid >> 6, lane = tid & 63;
    if (lane == 0) { sh[wave] = sc_; sh[8 + wave] = ss_; }
    __syncthreads();
    if (tid == 0) {
      float Sc = sh[0] + sh[1] + sh[2] + sh[3];
      float Ss = sh[8] + sh[9] + sh[10] + sh[11];
      tpl[2047 + d] = Sc + Ss;
      if (d > 0) tpl[2047 - d] = Sc - Ss;
    }
  } else if (b < 7232) {
    int t = b - 6144;   // W1 (DIMM x PROJ_) -> w1q (PROJ_ x DIMM) fp8 x64
    transpose_tile_fp8(W1, w1q, DIMM, PROJ_, t % 68, t / 68, sh);
  } else {
    int t = b - 7232;   // W2 (EXP x DIMM) -> w2q (DIMM x EXP) fp8 x64
    transpose_tile_fp8(W2, w2q, EXP, DIMM, t % 16, t / 16, sh);
  }
}

// =================== core A: implicit-drain dbuf (best for cache-resident operands: uv) ===================
__device__ __forceinline__ void mfma_core_sync(const unsigned char* __restrict__ A,
                                               const unsigned char* __restrict__ B,
                                               int K, long rowBase, long colBase,
                                               unsigned char* smem, floatx4 acc[4][4]) {
  const int tid  = threadIdx.x;
  const int wave = tid >> 6;
  const int lane = tid & 63;
  const int wr   = (wave >> 1) * 64;
  const int wc   = (wave & 1) * 64;
  const int r_l  = lane >> 3;
  const int c8   = lane & 7;
  const int fm   = lane & 15;
  const int fq   = lane >> 4;

  floatx4 z = {0.0f, 0.0f, 0.0f, 0.0f};
  #pragma unroll
  for (int mi = 0; mi < 4; ++mi)
    #pragma unroll
    for (int ni = 0; ni < 4; ++ni) acc[mi][ni] = z;

  const unsigned char* aSrc[4];
  const unsigned char* bSrc[4];
  int ldsOff[4];
  #pragma unroll
  for (int j = 0; j < 4; ++j) {
    int row = j * 32 + wave * 8 + r_l;
    int g = c8 ^ (row & 7);
    aSrc[j] = A + (rowBase + row) * (long)K + g * 16;
    bSrc[j] = B + (colBase + row) * (long)K + g * 16;
    ldsOff[j] = (j * 32 + wave * 8) * 128;
  }

  union U8 { uint4 q[2]; int8v v; };
  const int nt = K >> 7;

  #pragma unroll
  for (int j = 0; j < 4; ++j) {
    async16(aSrc[j], smem + ldsOff[j]);
    async16(bSrc[j], smem + 16384 + ldsOff[j]);
  }
  __syncthreads();

  int cur = 0;
  for (int t = 0; t < nt; ++t) {
    unsigned char* As = smem + cur * 32768;
    unsigned char* Bs = As + 16384;
    if (t + 1 < nt) {
      unsigned char* An = smem + (cur ^ 1) * 32768;
      int k0 = (t + 1) << 7;
      #pragma unroll
      for (int j = 0; j < 4; ++j) {
        async16(aSrc[j] + k0, An + ldsOff[j]);
        async16(bSrc[j] + k0, An + 16384 + ldsOff[j]);
      }
    }
    int8v av[4], bv[4];
    #pragma unroll
    for (int mi = 0; mi < 4; ++mi) {
      int row = wr + mi * 16 + fm;
      int s0 = (2 * fq) ^ (row & 7);
      U8 u;
      u.q[0] = *(const uint4*)(As + row * 128 + s0 * 16);
      u.q[1] = *(const uint4*)(As + row * 128 + (s0 ^ 1) * 16);
      av[mi] = u.v;
    }
    #pragma unroll
    for (int ni = 0; ni < 4; ++ni) {
      int row = wc + ni * 16 + fm;
      int s0 = (2 * fq) ^ (row & 7);
      U8 u;
      u.q[0] = *(const uint4*)(Bs + row * 128 + s0 * 16);
      u.q[1] = *(const uint4*)(Bs + row * 128 + (s0 ^ 1) * 16);
      bv[ni] = u.v;
    }
    __builtin_amdgcn_s_setprio(1);
    #pragma unroll
    for (int mi = 0; mi < 4; ++mi)
      #pragma unroll
      for (int ni = 0; ni < 4; ++ni)
        acc[mi][ni] = __builtin_amdgcn_mfma_scale_f32_16x16x128_f8f6f4(
            av[mi], bv[ni], acc[mi][ni], 0, 0, 0, 0x7F7F7F7F, 0, 0x7F7F7F7F);
    __builtin_amdgcn_s_setprio(0);
    __syncthreads();
    cur ^= 1;
  }
}

// =================== core B: counted-vmcnt pipeline (best for HBM-streaming: qk/pv/out) ===================
__device__ __forceinline__ void mfma_core_pipe(const unsigned char* __restrict__ A,
                                               const unsigned char* __restrict__ B,
                                               int K, long rowBase, long colBase,
                                               unsigned char* smem, floatx4 acc[4][4]) {
  const int tid  = threadIdx.x;
  const int wave = tid >> 6;
  const int lane = tid & 63;
  const int wr   = (wave >> 1) * 64;
  const int wc   = (wave & 1) * 64;
  const int r_l  = lane >> 3;
  const int c8   = lane & 7;
  const int fm   = lane & 15;
  const int fq   = lane >> 4;

  floatx4 z = {0.0f, 0.0f, 0.0f, 0.0f};
  #pragma unroll
  for (int mi = 0; mi < 4; ++mi)
    #pragma unroll
    for (int ni = 0; ni < 4; ++ni) acc[mi][ni] = z;

  const unsigned char* aSrc[4];
  const unsigned char* bSrc[4];
  int ldsOff[4];
  #pragma unroll
  for (int j = 0; j < 4; ++j) {
    int row = j * 32 + wave * 8 + r_l;
    int g = c8 ^ (row & 7);
    aSrc[j] = A + (rowBase + row) * (long)K + g * 16;
    bSrc[j] = B + (colBase + row) * (long)K + g * 16;
    ldsOff[j] = (j * 32 + wave * 8) * 128;
  }

  union U8 { uint4 q[2]; int8v v; };
  const int nt = K >> 7;

  // prologue: stage tile 0 -> buf0 and (if present) tile 1 -> buf1
  #pragma unroll
  for (int j = 0; j < 4; ++j) {
    async16(aSrc[j], smem + ldsOff[j]);
    async16(bSrc[j], smem + 16384 + ldsOff[j]);
  }
  if (nt > 1) {
    #pragma unroll
    for (int j = 0; j < 4; ++j) {
      async16(aSrc[j] + 128, smem + 32768 + ldsOff[j]);
      async16(bSrc[j] + 128, smem + 49152 + ldsOff[j]);
    }
  }

  int cur = 0;
  for (int t = 0; t < nt; ++t) {
    // drain THIS tile's 8 loads; leave next tile's 8 in flight
    if (t + 1 < nt) {
      asm volatile("s_waitcnt vmcnt(8)" ::: "memory");
    } else {
      asm volatile("s_waitcnt vmcnt(0)" ::: "memory");
    }
    __builtin_amdgcn_s_barrier();          // all threads' tile-t data resident
    __builtin_amdgcn_sched_barrier(0);     // don't hoist ds_reads above the wait

    const unsigned char* As = smem + cur * 32768;
    const unsigned char* Bs = As + 16384;
    int8v av[4], bv[4];
    #pragma unroll
    for (int mi = 0; mi < 4; ++mi) {
      int row = wr + mi * 16 + fm;
      int s0 = (2 * fq) ^ (row & 7);
      U8 u;
      u.q[0] = *(const uint4*)(As + row * 128 + s0 * 16);
      u.q[1] = *(const uint4*)(As + row * 128 + (s0 ^ 1) * 16);
      av[mi] = u.v;
    }
    #pragma unroll
    for (int ni = 0; ni < 4; ++ni) {
      int row = wc + ni * 16 + fm;
      int s0 = (2 * fq) ^ (row & 7);
      U8 u;
      u.q[0] = *(const uint4*)(Bs + row * 128 + s0 * 16);
      u.q[1] = *(const uint4*)(Bs + row * 128 + (s0 ^ 1) * 16);
      bv[ni] = u.v;
    }
    asm volatile("s_waitcnt lgkmcnt(0)" ::: "memory");  // per-thread reads done
    __builtin_amdgcn_sched_barrier(0);
    __builtin_amdgcn_s_barrier();          // ALL threads done reading buf cur

    // reuse buf cur for tile t+2; flight overlaps the MFMA below
    if (t + 2 < nt) {
      unsigned char* nb = smem + cur * 32768;
      int k0 = (t + 2) << 7;
      #pragma unroll
      for (int j = 0; j < 4; ++j) {
        async16(aSrc[j] + k0, nb + ldsOff[j]);
        async16(bSrc[j] + k0, nb + 16384 + ldsOff[j]);
      }
    }

    __builtin_amdgcn_s_setprio(1);
    #pragma unroll
    for (int mi = 0; mi < 4; ++mi)
      #pragma unroll
      for (int ni = 0; ni < 4; ++ni)
        acc[mi][ni] = __builtin_amdgcn_mfma_scale_f32_16x16x128_f8f6f4(
            av[mi], bv[ni], acc[mi][ni], 0, 0, 0, 0x7F7F7F7F, 0, 0x7F7F7F7F);
    __builtin_amdgcn_s_setprio(0);
    cur ^= 1;
  }
}

#define EPILOGUE_VARS                                         \
  const int lane = threadIdx.x & 63, wave = threadIdx.x >> 6; \
  const int wr = (wave >> 1) * 64, wc = (wave & 1) * 64;      \
  const int fr = (lane >> 4) * 4, fc = lane & 15;

// ------------- GEMM1: split u(fp8 x64), vT(fp8), q/k(fp8 x64) -------------
__global__ void __launch_bounds__(256)
gemm_uv(const unsigned char* __restrict__ xq,
        const unsigned char* __restrict__ w1q,
        const float* __restrict__ b1,
        const float* __restrict__ gamma,
        const float* __restrict__ beta,
        unsigned char* __restrict__ uq,
        unsigned char* __restrict__ vT,
        unsigned char* __restrict__ qq,
        unsigned char* __restrict__ kq) {
  __shared__ __align__(16) unsigned char smem8[65536];  // dbuf core = 64 KB
  floatx4 acc[4][4];
  long rowBase = (long)blockIdx.x * 128;
  long colBase = (long)blockIdx.y * 128;
  mfma_core_sync(xq, w1q, DIMM, rowBase, colBase, smem8, acc);
  EPILOGUE_VARS

  if (blockIdx.y < 8) {
    #pragma unroll
    for (int ni = 0; ni < 4; ++ni) {
      long col = colBase + wc + ni * 16 + fc;
      float bb = b1[col];
      #pragma unroll
      for (int mi = 0; mi < 4; ++mi)
      #pragma unroll
      for (int i = 0; i < 4; ++i) {
        long row = rowBase + wr + mi * 16 + fr + i;
        float t = acc[mi][ni][i] * INV4096 + bb;
        uq[row * EXP + col] = f2fp8(t / (1.0f + __expf(-t)) * W8);
      }
    }
  } else if (blockIdx.y < 16) {
    // v region: direct fp8 pack (4-run along n) -> LDS [e-local][n-local]
    __syncthreads();
    #pragma unroll
    for (int ni = 0; ni < 4; ++ni) {
      int cl = wc + ni * 16 + fc;         // e-local
      float bb = b1[colBase + cl];
      #pragma unroll
      for (int mi = 0; mi < 4; ++mi) {
        int rl = wr + mi * 16 + fr;       // n-local, 4-run via i
        float v[4];
        #pragma unroll
        for (int i = 0; i < 4; ++i) {
          float t = acc[mi][ni][i] * INV4096 + bb;
          v[i] = t / (1.0f + __expf(-t));
        }
        *(unsigned int*)(smem8 + cl * 136 + rl) = pk4fp8(v[0], v[1], v[2], v[3]);
      }
    }
    __syncthreads();
    long b_   = rowBase >> 11;
    long nblk = rowBase & 2047;
    long e0   = colBase - EXP;
    #pragma unroll
    for (int rep = 0; rep < 4; ++rep) {
      int cl = rep * 32 + (threadIdx.x >> 3);
      int n0 = (threadIdx.x & 7) * 16;
      uint4 v16 = *(const uint4*)(smem8 + cl * 136 + n0);
      *(uint4*)(vT + (b_ * EXP + e0 + cl) * (long)SEQ + nblk + n0) = v16;
    }
  } else {
    #pragma unroll
    for (int ni = 0; ni < 4; ++ni) {
      long col = colBase + wc + ni * 16 + fc;
      int dd = (int)(col - 2 * EXP);
      float bb = b1[col];
      float g0 = gamma[dd], g1 = gamma[SH + dd];
      float be0 = beta[dd], be1 = beta[SH + dd];
      #pragma unroll
      for (int mi = 0; mi < 4; ++mi)
      #pragma unroll
      for (int i = 0; i < 4; ++i) {
        long row = rowBase + wr + mi * 16 + fr + i;
        float t = acc[mi][ni][i] * INV4096 + bb;
        float s = t / (1.0f + __expf(-t));
        qq[row * SH + dd] = f2fp8((s * g0 + be0) * W8);
        kq[row * SH + dd] = f2fp8((s * g1 + be1) * W8);
      }
    }
  }
}

// ------------- QK (swapped: A=k rows m, B=q rows n -> C=S^T[m][n]) -------------
// Slim LDS (33.5 KB -> 4 blocks/CU) + tpl window staged into LDS.
__global__ void __launch_bounds__(256)
gemm_qk(const unsigned char* __restrict__ kq,
        const unsigned char* __restrict__ qq,
        const float* __restrict__ tpl,
        unsigned char* __restrict__ ker) {
  __shared__ __align__(16) unsigned char smem8[33792];  // 32K core (nt=1) + 1K tpl window
  float* tplS = (float*)(smem8 + 32768);
  floatx4 acc[4][4];
  int L = blockIdx.x;
  long b = L & 7;                 // XCD-resident batch
  int w = L >> 3;                 // 0..255
  long mBase = (long)(w & 15) * 128;
  long nBase = (long)(w >> 4) * 128;
  // stage the 255-diagonal tpl window: indices (n-m+2047) for this tile
  long D = nBase - mBase;         // multiple of 128
  if (threadIdx.x < 64)
    ((float4*)tplS)[threadIdx.x] = *(const float4*)(tpl + D + 1920 + 4 * (long)threadIdx.x);
  mfma_core_pipe(kq + b * SEQ * SH, qq + b * SEQ * SH, SH, mBase, nBase, smem8, acc);
  unsigned char* kerb = ker + b * (long)SEQ * SEQ;
  EPILOGUE_VARS
  (void)fr;
  __syncthreads();  // all waves done with staged tiles; reuse smem8 as [n][m] tile
  #pragma unroll
  for (int mi = 0; mi < 4; ++mi)
  #pragma unroll
  for (int ni = 0; ni < 4; ++ni) {
    int m_loc0 = wr + mi * 16 + (lane >> 4) * 4;   // 4-run along m (A-rows)
    int n_loc  = wc + ni * 16 + fc;
    float v[4];
    #pragma unroll
    for (int i = 0; i < 4; ++i) {
      float val = acc[mi][ni][i] * QK_INV + tplS[n_loc - m_loc0 - i + 127];
      float r = fmaxf(val, 0.0f);
      v[i] = fminf(r * r * KER_SCALE, 440.0f);
    }
    *(unsigned int*)(smem8 + n_loc * 136 + m_loc0) = pk4fp8(v[0], v[1], v[2], v[3]);
  }
  __syncthreads();
  #pragma unroll
  for (int rep = 0; rep < 4; ++rep) {
    int n_loc = rep * 32 + (threadIdx.x >> 3);
    int m_seg = (threadIdx.x & 7) * 16;
    uint4 v16 = *(const uint4*)(smem8 + n_loc * 136 + m_seg);
    *(uint4*)(kerb + (nBase + n_loc) * (long)SEQ + mBase + m_seg) = v16;
  }
}

// ------------- PV (swapped: A=vT rows e, B=ker rows n -> C[e][n]) -------------
// obq[n][e] = fp8(acc * 2^-14 * u*64); u fused at pack (hw fp8 decode).
__global__ void __launch_bounds__(256)
gemm_pv(const unsigned char* __restrict__ ker,
        const unsigned char* __restrict__ vT,
        const unsigned char* __restrict__ uq,
        unsigned char* __restrict__ obq) {
  __shared__ __align__(16) unsigned char smem8[65536];
  floatx4 acc[4][4];
  int L = blockIdx.x;
  long b = L & 7;
  int w = L >> 3;                 // 0..127
  long eBase = (long)(w & 7) * 128;    // e fastest: ker n-slice reuse in L2
  long nBase = (long)(w >> 3) * 128;
  mfma_core_pipe(vT + b * (long)EXP * SEQ, ker + b * (long)SEQ * SEQ, SEQ,
                 eBase, nBase, smem8, acc);
  const unsigned char* ub = uq + b * (long)SEQ * EXP;
  unsigned char* obb = obq + b * (long)SEQ * EXP;
  EPILOGUE_VARS
  (void)fr;
  __syncthreads();  // reuse smem8 as [n][e] tile
  #pragma unroll
  for (int mi = 0; mi < 4; ++mi)
  #pragma unroll
  for (int ni = 0; ni < 4; ++ni) {
    int e_loc0 = wr + mi * 16 + (lane >> 4) * 4;   // 4-run along e (A-rows)
    int n_loc  = wc + ni * 16 + fc;
    unsigned int uw = *(const unsigned int*)(ub + (nBase + n_loc) * (long)EXP + eBase + e_loc0);
    float u0 = FP8DEC0(uw), u1 = FP8DEC1(uw), u2 = FP8DEC2(uw), u3 = FP8DEC3(uw);
    float v0 = acc[mi][ni][0] * KER_SCALE_INV * u0;
    float v1 = acc[mi][ni][1] * KER_SCALE_INV * u1;
    float v2 = acc[mi][ni][2] * KER_SCALE_INV * u2;
    float v3 = acc[mi][ni][3] * KER_SCALE_INV * u3;
    *(unsigned int*)(smem8 + n_loc * 136 + e_loc0) = pk4fp8(v0, v1, v2, v3);
  }
  __syncthreads();
  #pragma unroll
  for (int rep = 0; rep < 4; ++rep) {
    int n_loc = rep * 32 + (threadIdx.x >> 3);
    int e_seg = (threadIdx.x & 7) * 16;
    uint4 v16 = *(const uint4*)(smem8 + n_loc * 136 + e_seg);
    *(uint4*)(obb + (nBase + n_loc) * (long)EXP + eBase + e_seg) = v16;
  }
}

// ------------- OUT: out = (obq/64) @ (W2) + b2 + x -------------
__global__ void __launch_bounds__(256)
gemm_out(const unsigned char* __restrict__ obq,
         const unsigned char* __restrict__ w2q,
         const float* __restrict__ b2,
         const float* __restrict__ x,
         float* __restrict__ out) {
  __shared__ __align__(16) unsigned char smem8[65536];
  floatx4 acc[4][4];
  long rowBase = (long)blockIdx.x * 128;
  long colBase = (long)blockIdx.y * 128;
  mfma_core_pipe(obq, w2q, EXP, rowBase, colBase, smem8, acc);
  EPILOGUE_VARS
  #pragma unroll
  for (int mi = 0; mi < 4; ++mi)
  #pragma unroll
  for (int ni = 0; ni < 4; ++ni)
  #pragma unroll
  for (int i = 0; i < 4; ++i) {
    long row = rowBase + wr + mi * 16 + fr + i;
    long col = colBase + wc + ni * 16 + fc;
    out[row * DIMM + col] = acc[mi][ni][i] * INV4096 + b2[col] + x[row * DIMM + col];
  }
}

extern "C" void kernel_launch(void* const* d_in, const int* in_sizes, int n_in,
                              void* d_out, int out_size, void* d_ws, size_t ws_size,
                              hipStream_t stream) {
  const float* x          = (const float*)d_in[0];
  const float* W1         = (const float*)d_in[1];
  const float* b1         = (const float*)d_in[2];
  const float* W2         = (const float*)d_in[3];
  const float* b2         = (const float*)d_in[4];
  const float* rope_a     = (const float*)d_in[5];
  const float* rope_b     = (const float*)d_in[6];
  const float* gamma      = (const float*)d_in[7];
  const float* beta       = (const float*)d_in[8];
  const float* norm_scale = (const float*)d_in[9];
  float* out = (float*)d_out;

  char* ws = (char*)d_ws;
  size_t off = 0;
  auto nxt = [&](size_t bytes) -> void* {
    void* p = ws + off;
    off += (bytes + 255) & ~(size_t)255;
    return p;
  };
  unsigned char*  xq  = (unsigned char*)nxt((size_t)ROWS * DIMM);
  unsigned char*  w1q = (unsigned char*)nxt((size_t)PROJ_ * DIMM);
  unsigned char*  w2q = (unsigned char*)nxt((size_t)DIMM * EXP);
  unsigned char*  uq  = (unsigned char*)nxt((size_t)ROWS * EXP);
  unsigned char*  vT  = (unsigned char*)nxt((size_t)NBATCH * EXP * SEQ);
  unsigned char*  qq  = (unsigned char*)nxt((size_t)ROWS * SH);
  unsigned char*  kq  = (unsigned char*)nxt((size_t)ROWS * SH);
  float*          tpl = (float*)nxt((size_t)4096 * 4);
  unsigned char*  ker = (unsigned char*)nxt((size_t)NBATCH * SEQ * SEQ);
  unsigned char*  obq = (unsigned char*)nxt((size_t)ROWS * EXP);

  prep_kernel<<<7744, 256, 0, stream>>>(x, norm_scale, xq, W1, w1q, W2, w2q,
                                        rope_a, rope_b, tpl);
  gemm_uv<<<dim3(ROWS / 128, PROJ_ / 128), 256, 0, stream>>>(xq, w1q, b1, gamma, beta,
                                                             uq, vT, qq, kq);
  gemm_qk<<<2048, 256, 0, stream>>>(kq, qq, tpl, ker);
  gemm_pv<<<1024, 256, 0, stream>>>(ker, vT, uq, obq);
  gemm_out<<<dim3(ROWS / 128, DIMM / 128), 256, 0, stream>>>(obq, w2q, b2, x, out);
}

// Round 21
// 209.850 us; speedup vs baseline: 1.0448x; 1.0448x over previous
//
#include <hip/hip_runtime.h>
#include <math.h>

#define SEQ    2048
#define DIMM   512
#define SH     128
#define EXP    1024
#define PROJ_  2176
#define NBATCH 8
#define ROWS   16384  // NBATCH*SEQ

#define KER_SCALE     16384.0f
#define KER_SCALE_INV (1.0f / 16384.0f)
#define QK_INV        (1.0f / (4096.0f * 2048.0f))   // q,k scaled x64 each; /MAX_LEN
#define W8            64.0f                          // generic fp8 pre-scale
#define INV4096       (1.0f / 4096.0f)               // undo x64 * x64

typedef __attribute__((ext_vector_type(4))) float floatx4;
typedef __attribute__((ext_vector_type(8))) int   int8v;

__device__ __forceinline__ unsigned short f2bf(float f) {
  union { float f; unsigned int u; } v; v.f = f;
  unsigned int r = (v.u + 0x7fffu + ((v.u >> 16) & 1u)) >> 16;
  return (unsigned short)r;
}
__device__ __forceinline__ float bf2f(unsigned short h) {
  union { unsigned int u; float f; } v; v.u = ((unsigned int)h) << 16;
  return v.f;
}
__device__ __forceinline__ unsigned char f2fp8(float f) {
  return (unsigned char)(__builtin_amdgcn_cvt_pk_fp8_f32(f, 0.0f, 0, false) & 0xffu);
}
__device__ __forceinline__ unsigned int pk4fp8(float a, float b, float c, float d) {
  unsigned int w = __builtin_amdgcn_cvt_pk_fp8_f32(a, b, 0, false);
  return __builtin_amdgcn_cvt_pk_fp8_f32(c, d, w, true);
}
__device__ __forceinline__ float fp82f(unsigned char b) {
  int e = (b >> 3) & 15, m = b & 7;
  float v = ldexpf((float)(e ? (8 + m) : m), (e ? e : 1) - 10);
  return (b & 0x80) ? -v : v;
}

// hardware fp8(e4m3, OCP)->f32 decode; sel MUST be a literal constant 0..3
#if defined(__has_builtin)
#if __has_builtin(__builtin_amdgcn_cvt_f32_fp8)
#define HAVE_HW_FP8DEC 1
#endif
#endif
#ifdef HAVE_HW_FP8DEC
#define FP8DEC0(w) __builtin_amdgcn_cvt_f32_fp8((w), 0)
#define FP8DEC1(w) __builtin_amdgcn_cvt_f32_fp8((w), 1)
#define FP8DEC2(w) __builtin_amdgcn_cvt_f32_fp8((w), 2)
#define FP8DEC3(w) __builtin_amdgcn_cvt_f32_fp8((w), 3)
#else
#define FP8DEC0(w) fp82f((unsigned char)((w)))
#define FP8DEC1(w) fp82f((unsigned char)((w) >> 8))
#define FP8DEC2(w) fp82f((unsigned char)((w) >> 16))
#define FP8DEC3(w) fp82f((unsigned char)((w) >> 24))
#endif

__device__ __forceinline__ void async16(const void* g, void* l) {
  __builtin_amdgcn_global_load_lds(
      (const __attribute__((address_space(1))) void*)g,
      (__attribute__((address_space(3))) void*)l, 16, 0, 0);
}

// =================== fused prep (256 threads) ===================
__device__ __forceinline__ void transpose_tile_fp8(const float* __restrict__ in,
                                                   unsigned char* __restrict__ out,
                                                   int R, int C, int bx, int by, float* tile) {
  int tx = threadIdx.x & 31, ty = threadIdx.x >> 5;
  int c0 = bx * 32, r0 = by * 32;
  #pragma unroll
  for (int j = 0; j < 32; j += 8)
    tile[(ty + j) * 33 + tx] = in[(long)(r0 + ty + j) * C + c0 + tx];
  __syncthreads();
  #pragma unroll
  for (int j = 0; j < 32; j += 8)
    out[(long)(c0 + ty + j) * R + r0 + tx] = f2fp8(tile[tx * 33 + ty + j] * W8);
}

__global__ void prep_kernel(const float* __restrict__ x, const float* __restrict__ ns,
                            unsigned char* __restrict__ xq,
                            const float* __restrict__ W1, unsigned char* __restrict__ w1q,
                            const float* __restrict__ W2, unsigned char* __restrict__ w2q,
                            const float* __restrict__ ra, const float* __restrict__ rb,
                            float* __restrict__ tpl) {
  __shared__ float sh[33 * 32];
  const int b = blockIdx.x, tid = threadIdx.x;
  if (b < 4096) {
    // ---- RMSNorm -> fp8 x64: 4 rows per block ----
    int wave = tid >> 6, lane = tid & 63;
    long row = (long)b * 4 + wave;
    const float4* xr = (const float4*)(x + row * DIMM);
    float4 v0 = xr[lane], v1 = xr[lane + 64];
    float ss = v0.x*v0.x + v0.y*v0.y + v0.z*v0.z + v0.w*v0.w
             + v1.x*v1.x + v1.y*v1.y + v1.z*v1.z + v1.w*v1.w;
    #pragma unroll
    for (int o = 32; o > 0; o >>= 1) ss += __shfl_xor(ss, o);
    float sc = rsqrtf(ss * (1.0f / DIMM) + 1e-6f) * ns[0] * W8;
    uint2 pk;
    pk.x = pk4fp8(v0.x*sc, v0.y*sc, v0.z*sc, v0.w*sc);
    pk.y = pk4fp8(v1.x*sc, v1.y*sc, v1.z*sc, v1.w*sc);
    ((uint2*)(xq + row * DIMM))[lane] = pk;
  } else if (b < 6144) {
    // ---- toeplitz diagonals, paired: tpl(d)=Sc+Ss, tpl(-d)=Sc-Ss ----
    const int d = b - 4096;          // 0..2047
    float sc_ = 0.0f, ss_ = 0.0f;
    for (int k = tid; k < 1024; k += 256) {
      float a1 = ra[k], a2 = ra[k + 1024];
      float b1v = rb[k], b2v = rb[k + 1024];
      float p = a1 * b1v + a2 * b2v;
      float q = a1 * b2v - a2 * b1v;
      float th = exp2f((float)k * (-13.287712379549449f / 1024.0f));
      float ang = (float)d * th;
      sc_ += p * cosf(ang);
      ss_ += q * sinf(ang);
    }
    #pragma unroll
    for (int o = 32; o > 0; o >>= 1) {
      sc_ += __shfl_xor(sc_, o);
      ss_ += __shfl_xor(ss_, o);
    }
    int wave = tid >> 6, lane = tid & 63;
    if (lane == 0) { sh[wave] = sc_; sh[8 + wave] = ss_; }
    __syncthreads();
    if (tid == 0) {
      float Sc = sh[0] + sh[1] + sh[2] + sh[3];
      float Ss = sh[8] + sh[9] + sh[10] + sh[11];
      tpl[2047 + d] = Sc + Ss;
      if (d > 0) tpl[2047 - d] = Sc - Ss;
    }
  } else if (b < 7232) {
    int t = b - 6144;   // W1 (DIMM x PROJ_) -> w1q (PROJ_ x DIMM) fp8 x64
    transpose_tile_fp8(W1, w1q, DIMM, PROJ_, t % 68, t / 68, sh);
  } else {
    int t = b - 7232;   // W2 (EXP x DIMM) -> w2q (DIMM x EXP) fp8 x64
    transpose_tile_fp8(W2, w2q, EXP, DIMM, t % 16, t / 16, sh);
  }
}

// =================== counted-vmcnt pipelined MX-fp8 MFMA core, BK=128 ===================
// C(128x128) = A . B^T ; A,B row-major fp8 e4m3, ld = K (K%128==0).
// 2 LDS buffers (64 KiB), loads kept 2 tiles in flight; per-iter wait is
// s_waitcnt vmcnt(8) (drain current tile's 8 loads only) -- NOT vmcnt(0).
// The buffer-recycle barrier (lgkmcnt+s_barrier) is emitted ONLY when a
// tile t+2 will actually be staged; tail iterations skip it (register
// deps for the MFMA are compiler-tracked since ds_reads are C++ loads).
__device__ __forceinline__ void mfma_core_mx(const unsigned char* __restrict__ A,
                                             const unsigned char* __restrict__ B,
                                             int K, long rowBase, long colBase,
                                             unsigned char* smem, floatx4 acc[4][4]) {
  const int tid  = threadIdx.x;
  const int wave = tid >> 6;
  const int lane = tid & 63;
  const int wr   = (wave >> 1) * 64;
  const int wc   = (wave & 1) * 64;
  const int r_l  = lane >> 3;
  const int c8   = lane & 7;
  const int fm   = lane & 15;
  const int fq   = lane >> 4;

  floatx4 z = {0.0f, 0.0f, 0.0f, 0.0f};
  #pragma unroll
  for (int mi = 0; mi < 4; ++mi)
    #pragma unroll
    for (int ni = 0; ni < 4; ++ni) acc[mi][ni] = z;

  const unsigned char* aSrc[4];
  const unsigned char* bSrc[4];
  int ldsOff[4];
  #pragma unroll
  for (int j = 0; j < 4; ++j) {
    int row = j * 32 + wave * 8 + r_l;
    int g = c8 ^ (row & 7);
    aSrc[j] = A + (rowBase + row) * (long)K + g * 16;
    bSrc[j] = B + (colBase + row) * (long)K + g * 16;
    ldsOff[j] = (j * 32 + wave * 8) * 128;
  }

  union U8 { uint4 q[2]; int8v v; };
  const int nt = K >> 7;

  // prologue: stage tile 0 -> buf0 and (if present) tile 1 -> buf1
  #pragma unroll
  for (int j = 0; j < 4; ++j) {
    async16(aSrc[j], smem + ldsOff[j]);
    async16(bSrc[j], smem + 16384 + ldsOff[j]);
  }
  if (nt > 1) {
    #pragma unroll
    for (int j = 0; j < 4; ++j) {
      async16(aSrc[j] + 128, smem + 32768 + ldsOff[j]);
      async16(bSrc[j] + 128, smem + 49152 + ldsOff[j]);
    }
  }

  int cur = 0;
  for (int t = 0; t < nt; ++t) {
    // drain THIS tile's 8 loads; leave next tile's 8 in flight
    if (t + 1 < nt) {
      asm volatile("s_waitcnt vmcnt(8)" ::: "memory");
    } else {
      asm volatile("s_waitcnt vmcnt(0)" ::: "memory");
    }
    __builtin_amdgcn_s_barrier();          // all threads' tile-t data resident
    __builtin_amdgcn_sched_barrier(0);     // don't hoist ds_reads above the wait

    const unsigned char* As = smem + cur * 32768;
    const unsigned char* Bs = As + 16384;
    int8v av[4], bv[4];
    #pragma unroll
    for (int mi = 0; mi < 4; ++mi) {
      int row = wr + mi * 16 + fm;
      int s0 = (2 * fq) ^ (row & 7);
      U8 u;
      u.q[0] = *(const uint4*)(As + row * 128 + s0 * 16);
      u.q[1] = *(const uint4*)(As + row * 128 + (s0 ^ 1) * 16);
      av[mi] = u.v;
    }
    #pragma unroll
    for (int ni = 0; ni < 4; ++ni) {
      int row = wc + ni * 16 + fm;
      int s0 = (2 * fq) ^ (row & 7);
      U8 u;
      u.q[0] = *(const uint4*)(Bs + row * 128 + s0 * 16);
      u.q[1] = *(const uint4*)(Bs + row * 128 + (s0 ^ 1) * 16);
      bv[ni] = u.v;
    }
    if (t + 2 < nt) {
      // buffer recycle: all threads must be done reading buf cur first
      asm volatile("s_waitcnt lgkmcnt(0)" ::: "memory");
      __builtin_amdgcn_sched_barrier(0);
      __builtin_amdgcn_s_barrier();
      unsigned char* nb = smem + cur * 32768;
      int k0 = (t + 2) << 7;
      #pragma unroll
      for (int j = 0; j < 4; ++j) {
        async16(aSrc[j] + k0, nb + ldsOff[j]);
        async16(bSrc[j] + k0, nb + 16384 + ldsOff[j]);
      }
    }

    __builtin_amdgcn_s_setprio(1);
    #pragma unroll
    for (int mi = 0; mi < 4; ++mi)
      #pragma unroll
      for (int ni = 0; ni < 4; ++ni)
        acc[mi][ni] = __builtin_amdgcn_mfma_scale_f32_16x16x128_f8f6f4(
            av[mi], bv[ni], acc[mi][ni], 0, 0, 0, 0x7F7F7F7F, 0, 0x7F7F7F7F);
    __builtin_amdgcn_s_setprio(0);
    cur ^= 1;
  }
}

#define EPILOGUE_VARS                                         \
  const int lane = threadIdx.x & 63, wave = threadIdx.x >> 6; \
  const int wr = (wave >> 1) * 64, wc = (wave & 1) * 64;      \
  const int fr = (lane >> 4) * 4, fc = lane & 15;

// ------------- GEMM1: split u(fp8 x64), vT(fp8), q/k(fp8 x64) -------------
__global__ void __launch_bounds__(256)
gemm_uv(const unsigned char* __restrict__ xq,
        const unsigned char* __restrict__ w1q,
        const float* __restrict__ b1,
        const float* __restrict__ gamma,
        const float* __restrict__ beta,
        unsigned char* __restrict__ uq,
        unsigned char* __restrict__ vT,
        unsigned char* __restrict__ qq,
        unsigned char* __restrict__ kq) {
  __shared__ __align__(16) unsigned char smem8[65536];  // dbuf core = 64 KB
  floatx4 acc[4][4];
  long rowBase = (long)blockIdx.x * 128;
  long colBase = (long)blockIdx.y * 128;
  mfma_core_mx(xq, w1q, DIMM, rowBase, colBase, smem8, acc);
  EPILOGUE_VARS

  if (blockIdx.y < 8) {
    #pragma unroll
    for (int ni = 0; ni < 4; ++ni) {
      long col = colBase + wc + ni * 16 + fc;
      float bb = b1[col];
      #pragma unroll
      for (int mi = 0; mi < 4; ++mi)
      #pragma unroll
      for (int i = 0; i < 4; ++i) {
        long row = rowBase + wr + mi * 16 + fr + i;
        float t = acc[mi][ni][i] * INV4096 + bb;
        uq[row * EXP + col] = f2fp8(t / (1.0f + __expf(-t)) * W8);
      }
    }
  } else if (blockIdx.y < 16) {
    // v region: direct fp8 pack (4-run along n) -> LDS [e-local][n-local]
    __syncthreads();
    #pragma unroll
    for (int ni = 0; ni < 4; ++ni) {
      int cl = wc + ni * 16 + fc;         // e-local
      float bb = b1[colBase + cl];
      #pragma unroll
      for (int mi = 0; mi < 4; ++mi) {
        int rl = wr + mi * 16 + fr;       // n-local, 4-run via i
        float v[4];
        #pragma unroll
        for (int i = 0; i < 4; ++i) {
          float t = acc[mi][ni][i] * INV4096 + bb;
          v[i] = t / (1.0f + __expf(-t));
        }
        *(unsigned int*)(smem8 + cl * 136 + rl) = pk4fp8(v[0], v[1], v[2], v[3]);
      }
    }
    __syncthreads();
    long b_   = rowBase >> 11;
    long nblk = rowBase & 2047;
    long e0   = colBase - EXP;
    #pragma unroll
    for (int rep = 0; rep < 4; ++rep) {
      int cl = rep * 32 + (threadIdx.x >> 3);
      int n0 = (threadIdx.x & 7) * 16;
      uint4 v16 = *(const uint4*)(smem8 + cl * 136 + n0);
      *(uint4*)(vT + (b_ * EXP + e0 + cl) * (long)SEQ + nblk + n0) = v16;
    }
  } else {
    #pragma unroll
    for (int ni = 0; ni < 4; ++ni) {
      long col = colBase + wc + ni * 16 + fc;
      int dd = (int)(col - 2 * EXP);
      float bb = b1[col];
      float g0 = gamma[dd], g1 = gamma[SH + dd];
      float be0 = beta[dd], be1 = beta[SH + dd];
      #pragma unroll
      for (int mi = 0; mi < 4; ++mi)
      #pragma unroll
      for (int i = 0; i < 4; ++i) {
        long row = rowBase + wr + mi * 16 + fr + i;
        float t = acc[mi][ni][i] * INV4096 + bb;
        float s = t / (1.0f + __expf(-t));
        qq[row * SH + dd] = f2fp8((s * g0 + be0) * W8);
        kq[row * SH + dd] = f2fp8((s * g1 + be1) * W8);
      }
    }
  }
}

// ------------- QK (swapped: A=k rows m, B=q rows n -> C=S^T[m][n]) -------------
// Slim LDS (33.5 KB -> 4 blocks/CU) + tpl window staged into LDS.
__global__ void __launch_bounds__(256)
gemm_qk(const unsigned char* __restrict__ kq,
        const unsigned char* __restrict__ qq,
        const float* __restrict__ tpl,
        unsigned char* __restrict__ ker) {
  __shared__ __align__(16) unsigned char smem8[33792];  // 32K core (nt=1) + 1K tpl window
  float* tplS = (float*)(smem8 + 32768);
  floatx4 acc[4][4];
  int L = blockIdx.x;
  long b = L & 7;                 // XCD-resident batch
  int w = L >> 3;                 // 0..255
  long mBase = (long)(w & 15) * 128;
  long nBase = (long)(w >> 4) * 128;
  // stage the 255-diagonal tpl window: indices (n-m+2047) for this tile
  long D = nBase - mBase;         // multiple of 128
  if (threadIdx.x < 64)
    ((float4*)tplS)[threadIdx.x] = *(const float4*)(tpl + D + 1920 + 4 * (long)threadIdx.x);
  mfma_core_mx(kq + b * SEQ * SH, qq + b * SEQ * SH, SH, mBase, nBase, smem8, acc);
  unsigned char* kerb = ker + b * (long)SEQ * SEQ;
  EPILOGUE_VARS
  (void)fr;
  __syncthreads();  // all waves done with staged tiles; reuse smem8 as [n][m] tile
  #pragma unroll
  for (int mi = 0; mi < 4; ++mi)
  #pragma unroll
  for (int ni = 0; ni < 4; ++ni) {
    int m_loc0 = wr + mi * 16 + (lane >> 4) * 4;   // 4-run along m (A-rows)
    int n_loc  = wc + ni * 16 + fc;
    float v[4];
    #pragma unroll
    for (int i = 0; i < 4; ++i) {
      float val = acc[mi][ni][i] * QK_INV + tplS[n_loc - m_loc0 - i + 127];
      float r = fmaxf(val, 0.0f);
      v[i] = fminf(r * r * KER_SCALE, 440.0f);
    }
    *(unsigned int*)(smem8 + n_loc * 136 + m_loc0) = pk4fp8(v[0], v[1], v[2], v[3]);
  }
  __syncthreads();
  #pragma unroll
  for (int rep = 0; rep < 4; ++rep) {
    int n_loc = rep * 32 + (threadIdx.x >> 3);
    int m_seg = (threadIdx.x & 7) * 16;
    uint4 v16 = *(const uint4*)(smem8 + n_loc * 136 + m_seg);
    *(uint4*)(kerb + (nBase + n_loc) * (long)SEQ + mBase + m_seg) = v16;
  }
}

// ------------- PV (swapped: A=vT rows e, B=ker rows n -> C[e][n]) -------------
// obq[n][e] = fp8(acc * 2^-14 * u*64); u fused at pack (hw fp8 decode).
__global__ void __launch_bounds__(256)
gemm_pv(const unsigned char* __restrict__ ker,
        const unsigned char* __restrict__ vT,
        const unsigned char* __restrict__ uq,
        unsigned char* __restrict__ obq) {
  __shared__ __align__(16) unsigned char smem8[65536];
  floatx4 acc[4][4];
  int L = blockIdx.x;
  long b = L & 7;
  int w = L >> 3;                 // 0..127
  long eBase = (long)(w & 7) * 128;    // e fastest: ker n-slice reuse in L2
  long nBase = (long)(w >> 3) * 128;
  mfma_core_mx(vT + b * (long)EXP * SEQ, ker + b * (long)SEQ * SEQ, SEQ,
               eBase, nBase, smem8, acc);
  const unsigned char* ub = uq + b * (long)SEQ * EXP;
  unsigned char* obb = obq + b * (long)SEQ * EXP;
  EPILOGUE_VARS
  (void)fr;
  __syncthreads();  // reuse smem8 as [n][e] tile
  #pragma unroll
  for (int mi = 0; mi < 4; ++mi)
  #pragma unroll
  for (int ni = 0; ni < 4; ++ni) {
    int e_loc0 = wr + mi * 16 + (lane >> 4) * 4;   // 4-run along e (A-rows)
    int n_loc  = wc + ni * 16 + fc;
    unsigned int uw = *(const unsigned int*)(ub + (nBase + n_loc) * (long)EXP + eBase + e_loc0);
    float u0 = FP8DEC0(uw), u1 = FP8DEC1(uw), u2 = FP8DEC2(uw), u3 = FP8DEC3(uw);
    float v0 = acc[mi][ni][0] * KER_SCALE_INV * u0;
    float v1 = acc[mi][ni][1] * KER_SCALE_INV * u1;
    float v2 = acc[mi][ni][2] * KER_SCALE_INV * u2;
    float v3 = acc[mi][ni][3] * KER_SCALE_INV * u3;
    *(unsigned int*)(smem8 + n_loc * 136 + e_loc0) = pk4fp8(v0, v1, v2, v3);
  }
  __syncthreads();
  #pragma unroll
  for (int rep = 0; rep < 4; ++rep) {
    int n_loc = rep * 32 + (threadIdx.x >> 3);
    int e_seg = (threadIdx.x & 7) * 16;
    uint4 v16 = *(const uint4*)(smem8 + n_loc * 136 + e_seg);
    *(uint4*)(obb + (nBase + n_loc) * (long)EXP + eBase + e_seg) = v16;
  }
}

// ------------- OUT: out = (obq/64) @ (W2) + b2 + x -------------
__global__ void __launch_bounds__(256)
gemm_out(const unsigned char* __restrict__ obq,
         const unsigned char* __restrict__ w2q,
         const float* __restrict__ b2,
         const float* __restrict__ x,
         float* __restrict__ out) {
  __shared__ __align__(16) unsigned char smem8[65536];
  floatx4 acc[4][4];
  long rowBase = (long)blockIdx.x * 128;
  long colBase = (long)blockIdx.y * 128;
  mfma_core_mx(obq, w2q, EXP, rowBase, colBase, smem8, acc);
  EPILOGUE_VARS
  #pragma unroll
  for (int mi = 0; mi < 4; ++mi)
  #pragma unroll
  for (int ni = 0; ni < 4; ++ni)
  #pragma unroll
  for (int i = 0; i < 4; ++i) {
    long row = rowBase + wr + mi * 16 + fr + i;
    long col = colBase + wc + ni * 16 + fc;
    out[row * DIMM + col] = acc[mi][ni][i] * INV4096 + b2[col] + x[row * DIMM + col];
  }
}

extern "C" void kernel_launch(void* const* d_in, const int* in_sizes, int n_in,
                              void* d_out, int out_size, void* d_ws, size_t ws_size,
                              hipStream_t stream) {
  const float* x          = (const float*)d_in[0];
  const float* W1         = (const float*)d_in[1];
  const float* b1         = (const float*)d_in[2];
  const float* W2         = (const float*)d_in[3];
  const float* b2         = (const float*)d_in[4];
  const float* rope_a     = (const float*)d_in[5];
  const float* rope_b     = (const float*)d_in[6];
  const float* gamma      = (const float*)d_in[7];
  const float* beta       = (const float*)d_in[8];
  const float* norm_scale = (const float*)d_in[9];
  float* out = (float*)d_out;

  char* ws = (char*)d_ws;
  size_t off = 0;
  auto nxt = [&](size_t bytes) -> void* {
    void* p = ws + off;
    off += (bytes + 255) & ~(size_t)255;
    return p;
  };
  unsigned char*  xq  = (unsigned char*)nxt((size_t)ROWS * DIMM);
  unsigned char*  w1q = (unsigned char*)nxt((size_t)PROJ_ * DIMM);
  unsigned char*  w2q = (unsigned char*)nxt((size_t)DIMM * EXP);
  unsigned char*  uq  = (unsigned char*)nxt((size_t)ROWS * EXP);
  unsigned char*  vT  = (unsigned char*)nxt((size_t)NBATCH * EXP * SEQ);
  unsigned char*  qq  = (unsigned char*)nxt((size_t)ROWS * SH);
  unsigned char*  kq  = (unsigned char*)nxt((size_t)ROWS * SH);
  float*          tpl = (float*)nxt((size_t)4096 * 4);
  unsigned char*  ker = (unsigned char*)nxt((size_t)NBATCH * SEQ * SEQ);
  unsigned char*  obq = (unsigned char*)nxt((size_t)ROWS * EXP);

  prep_kernel<<<7744, 256, 0, stream>>>(x, norm_scale, xq, W1, w1q, W2, w2q,
                                        rope_a, rope_b, tpl);
  gemm_uv<<<dim3(ROWS / 128, PROJ_ / 128), 256, 0, stream>>>(xq, w1q, b1, gamma, beta,
                                                             uq, vT, qq, kq);
  gemm_qk<<<2048, 256, 0, stream>>>(kq, qq, tpl, ker);
  gemm_pv<<<1024, 256, 0, stream>>>(ker, vT, uq, obq);
  gemm_out<<<dim3(ROWS / 128, DIMM / 128), 256, 0, stream>>>(obq, w2q, b2, x, out);
}